// Round 11
// baseline (309.865 us; speedup 1.0000x reference)
//
#include <hip/hip_runtime.h>
#include <math.h>

// LeCun LCN, fused single kernel, radius-5 truncated Gaussian (taps d>=6 have
// total weight 1.2e-8 -- numerically invisible vs the 4.9e-2 threshold).
//
// mean     = gauss11x11 * x          (separable, zero-pad SAME)
// centered = x - mean
// var      = gauss11x11 * centered^2 (zero-pad SAME)
// out      = centered / (sqrt(var) + 1e-4) * mask
//
// R1: TH=16 lost 14% (occupancy bought with +25% halo work).
// R4: sliding register windows = -21% (245->194us).
// R7: conv-2 vblur->hblur swap = -6% (194->182us).
// R8: s1 ring 32 -> 4 blocks/CU: occ 26->34 but only -2% (178us).
//     Occupancy is NOT the lever; halo WORK is. Conflicts pinned at 1.02e7
//     across layouts -> structural b128 cost, not aliasing.
// R9: TH=64 rolling strip, 512 threads, s1 ring 48 (sub-chunked fills).
//     P1: 84 rows/64 out (was 104/64 as 2 tiles): -19% P1 work.
//     P2: 74/64 (was 84/64): -12%. Total conv outputs -10%.
//     Barriers 7 per 64 rows (was 12). LDS 64.4KB -> 2 blocks/CU = 16 waves.
//
//  s1h ring[48][132]: hblur(x), image rows h0-10..h0+73 streamed in 2 fills
//  b2      [74][132]: centered = x - vblur(s1)   (b2 row br = image h0-5+br)
//  vc (overlays s1h) [32][132]: vblur(b2^2), computed in 2 halves
//  P4: hblur(vc)=var + epilogue, per half, 256 tasks (row, 12-col run)

#define TW 32
#define TH 64
#define S1W 132          // LDS row stride (126 cols used + pad)
#define S1R 48           // s1 ring rows
#define B2R 74           // TH + 10
#define NT  512

__global__ __launch_bounds__(NT, 4)
void lecun_lcn_kernel(const float* __restrict__ x,
                      const float* __restrict__ mask,
                      float* __restrict__ out)
{
    __shared__ float s1h[S1R * S1W];   // 25,344 B (reused as vc[32][132])
    __shared__ float b2[B2R * S1W];    // 39,072 B  (total 64,416 -> 2 blocks/CU)

    const int tid = threadIdx.x;
    const int w0  = blockIdx.x * TW;
    const int h0  = blockIdx.y * TH;
    const int bi  = blockIdx.z;
    const int fc0 = 3 * w0 - 15;      // flat col of s1/b2/vc index 0

    // 1D Gaussian (std=1), taps 0..5, normalized by the full 19-tap sum.
    const float K[6] = {
        3.9894227826685783e-01f,
        2.4197072322439816e-01f,
        5.3990966224238430e-02f,
        4.4318483882270000e-03f,
        1.3383022504889000e-04f,
        1.4867195067806000e-06f
    };

    const float* xb = x + (size_t)bi * 512 * 1536;

    // ---- P1 task: hblur image row (h0-10+ss) into ring slot, 16-col run ----
    auto p1_task = [&](int ss, int slot, int run) {
        const int h = h0 - 10 + ss;
        float* dst = &s1h[slot * S1W + run * 16];
        if ((unsigned)h >= 512u) {
            float4 z = make_float4(0.f, 0.f, 0.f, 0.f);
            ((float4*)dst)[0] = z; ((float4*)dst)[1] = z;
            ((float4*)dst)[2] = z; ((float4*)dst)[3] = z;
            return;
        }
        const float* xrow = xb + (size_t)h * 1536;
        const int gc0 = fc0 + run * 16;    // first output flat col
        const int a   = gc0 - 17;          // window start; gc0%4==1 -> a%4==0
        float w[48];
        if (a >= 0 && a <= 1536 - 48) {
            const float4* p = (const float4*)(xrow + a);
            #pragma unroll
            for (int q = 0; q < 12; ++q) {
                float4 v = p[q];
                w[4*q+0] = v.x; w[4*q+1] = v.y; w[4*q+2] = v.z; w[4*q+3] = v.w;
            }
        } else {
            #pragma unroll
            for (int i = 0; i < 48; ++i) {
                int j = a + i;
                w[i] = ((unsigned)j < 1536u) ? xrow[j] : 0.0f;
            }
        }
        float v1[16];
        #pragma unroll
        for (int i = 0; i < 16; ++i) {
            const int ci = 17 + i;
            float acc = K[0] * w[ci];
            #pragma unroll
            for (int d = 1; d <= 5; ++d)
                acc = fmaf(K[d], w[ci - 3*d] + w[ci + 3*d], acc);
            v1[i] = acc;
        }
        ((float4*)dst)[0] = make_float4(v1[0],  v1[1],  v1[2],  v1[3]);
        ((float4*)dst)[1] = make_float4(v1[4],  v1[5],  v1[6],  v1[7]);
        ((float4*)dst)[2] = make_float4(v1[8],  v1[9],  v1[10], v1[11]);
        ((float4*)dst)[3] = make_float4(v1[12], v1[13], v1[14], v1[15]);
    };

    // ---- P2: produce cnt b2 rows from rb; sliding register window ----------
    auto p2_run = [&](int rb, int cnt) {
        const int quad = tid & 31;
        const int c4   = quad * 4;
        const int gcb  = fc0 + c4;
        const bool cv0 = (unsigned)(gcb + 0) < 1536u;
        const bool cv1 = (unsigned)(gcb + 1) < 1536u;
        const bool cv2 = (unsigned)(gcb + 2) < 1536u;
        const bool cv3 = (unsigned)(gcb + 3) < 1536u;
        float4 w[13];                      // s1 rows rb..rb+cnt+9 (ring)
        #pragma unroll
        for (int k = 0; k < 13; ++k) {
            if (k < cnt + 10) {
                const int ss = rb + k;
                const int sl = (ss >= S1R) ? ss - S1R : ss;
                w[k] = *(const float4*)&s1h[sl * S1W + c4];
            }
        }
        #pragma unroll
        for (int j = 0; j < 3; ++j) {
            if (j < cnt) {
                const int br = rb + j;
                const int h = h0 - 5 + br;
                float4* dst = (float4*)&b2[br * S1W + c4];
                if ((unsigned)h >= 512u) {
                    *dst = make_float4(0.f, 0.f, 0.f, 0.f);
                } else {
                    float m0 = K[0] * w[j+5].x, m1 = K[0] * w[j+5].y;
                    float m2 = K[0] * w[j+5].z, m3 = K[0] * w[j+5].w;
                    #pragma unroll
                    for (int d = 1; d <= 5; ++d) {
                        float4 aa = w[j + 5 - d];
                        float4 bb = w[j + 5 + d];
                        m0 = fmaf(K[d], aa.x + bb.x, m0);
                        m1 = fmaf(K[d], aa.y + bb.y, m1);
                        m2 = fmaf(K[d], aa.z + bb.z, m2);
                        m3 = fmaf(K[d], aa.w + bb.w, m3);
                    }
                    const float* xrow = xb + (size_t)h * 1536;
                    // out-of-image cols must be exact 0 (zero-pad of conv-2)
                    float c0 = cv0 ? (xrow[gcb + 0] - m0) : 0.0f;
                    float c1 = cv1 ? (xrow[gcb + 1] - m1) : 0.0f;
                    float c2 = cv2 ? (xrow[gcb + 2] - m2) : 0.0f;
                    float c3 = cv3 ? (xrow[gcb + 3] - m3) : 0.0f;
                    *dst = make_float4(c0, c1, c2, c3);
                }
            }
        }
    };

    // ---- P3 half: vblur(b2^2) -> vc rows vbase..vbase+31 (slots 0..31) -----
    float* vc = s1h;                       // s1 dead after P2b
    auto p3_half = [&](int vbase) {
        const int quad = tid & 31;
        const int rt   = tid >> 5;         // 0..15
        const int c4   = quad * 4;
        const int v0   = vbase + 2 * rt;   // output rows v0, v0+1
        float4 w[12];                      // b2sq rows v0..v0+11
        #pragma unroll
        for (int k = 0; k < 12; ++k) {
            float4 t = *(const float4*)&b2[(v0 + k) * S1W + c4];
            w[k] = make_float4(t.x*t.x, t.y*t.y, t.z*t.z, t.w*t.w);
        }
        #pragma unroll
        for (int j = 0; j < 2; ++j) {
            float s0 = K[0] * w[j+5].x, s1v = K[0] * w[j+5].y;
            float s2v = K[0] * w[j+5].z, s3 = K[0] * w[j+5].w;
            #pragma unroll
            for (int d = 1; d <= 5; ++d) {
                float4 aa = w[j + 5 - d];
                float4 bb = w[j + 5 + d];
                s0  = fmaf(K[d], aa.x + bb.x, s0);
                s1v = fmaf(K[d], aa.y + bb.y, s1v);
                s2v = fmaf(K[d], aa.z + bb.z, s2v);
                s3  = fmaf(K[d], aa.w + bb.w, s3);
            }
            *(float4*)&vc[(v0 - vbase + j) * S1W + c4] =
                make_float4(s0, s1v, s2v, s3);
        }
    };

    // ---- P4 half: hblur(vc)=var + epilogue, out rows rbase..rbase+31 -------
    auto p4_half = [&](int rbase) {
        if (tid >= 256) return;
        const int r    = rbase + (tid >> 3);
        const int run  = tid & 7;
        const int tc0  = run * 12;
        float w[44];                       // vc[r-rbase][tc0 .. tc0+43]
        #pragma unroll
        for (int q = 0; q < 11; ++q) {
            float4 v = *(const float4*)&vc[(r - rbase) * S1W + tc0 + 4*q];
            w[4*q+0] = v.x; w[4*q+1] = v.y; w[4*q+2] = v.z; w[4*q+3] = v.w;
        }
        // centered at b2 row r+5, rel floats 15..26: 4 aligned b128
        float cw[16];
        #pragma unroll
        for (int q = 0; q < 4; ++q) {
            float4 v = *(const float4*)&b2[(r + 5) * S1W + tc0 + 12 + 4*q];
            cw[4*q+0] = v.x; cw[4*q+1] = v.y; cw[4*q+2] = v.z; cw[4*q+3] = v.w;
        }
        const int h = h0 + r;
        const size_t rowoff = (size_t)(bi * 512 + h);
        const float* mrow = mask + rowoff * 512 + w0 + 4 * run;
        float mv[4];
        #pragma unroll
        for (int k = 0; k < 4; ++k) mv[k] = mrow[k];
        float o[12];
        #pragma unroll
        for (int j = 0; j < 12; ++j) {
            const int ci = 15 + j;
            float var = K[0] * w[ci];
            #pragma unroll
            for (int d = 1; d <= 5; ++d)
                var = fmaf(K[d], w[ci - 3*d] + w[ci + 3*d], var);
            o[j] = cw[j + 3] * __builtin_amdgcn_rcpf(sqrtf(var) + 1e-4f) * mv[j / 3];
        }
        float* orow = &out[rowoff * 1536 + 3 * w0 + tc0];
        ((float4*)orow)[0] = make_float4(o[0], o[1], o[2],  o[3]);
        ((float4*)orow)[1] = make_float4(o[4], o[5], o[6],  o[7]);
        ((float4*)orow)[2] = make_float4(o[8], o[9], o[10], o[11]);
    };

    // ---------------- schedule ----------------------------------------------
    // P1a: ss 0..47 -> slots 0..47 (384 tasks)
    if (tid < 384) p1_task(tid >> 3, tid >> 3, tid & 7);
    __syncthreads();

    // P2a: b2 rows 0..37 (needs ss 0..47)
    {
        const int rt  = tid >> 5;
        const int cnt = (rt < 6) ? 3 : 2;
        const int rb  = (rt < 6) ? 3 * rt : 18 + 2 * (rt - 6);
        p2_run(rb, cnt);
    }
    __syncthreads();

    // P1b: ss 48..83 -> slots 0..35 (288 tasks; slots 36..47 keep ss 36..47)
    if (tid < 288) p1_task(48 + (tid >> 3), tid >> 3, tid & 7);
    __syncthreads();

    // P2b: b2 rows 38..73 (needs ss 38..83: slots 38..47 old + 0..35 new)
    {
        const int rt  = tid >> 5;
        const int cnt = (rt < 4) ? 3 : 2;
        const int rb  = (rt < 4) ? 38 + 3 * rt : 50 + 2 * (rt - 4);
        p2_run(rb, cnt);
    }
    __syncthreads();

    p3_half(0);
    __syncthreads();
    p4_half(0);
    __syncthreads();      // P3b overwrites vc slots read by P4a
    p3_half(32);
    __syncthreads();
    p4_half(32);
}

extern "C" void kernel_launch(void* const* d_in, const int* in_sizes, int n_in,
                              void* d_out, int out_size, void* d_ws, size_t ws_size,
                              hipStream_t stream) {
    const float* x0   = (const float*)d_in[0];
    const float* mask = (const float*)d_in[1];
    float* out = (float*)d_out;

    dim3 grid(512 / TW, 512 / TH, 32);   // (16, 8, 32) = 4096 blocks
    dim3 block(NT);
    lecun_lcn_kernel<<<grid, block, 0, stream>>>(x0, mask, out);
}